// Round 7
// baseline (28.718 us; speedup 1.0000x reference)
//
#include <hip/hip_runtime.h>

#define NH 64
#define LFULL 2048
#define MH 1024
#define KSTRIDE 1028   // float2 stride per head for Kf rows in ws (16B-aligned rows)
#define PI_F 3.14159265358979323846f
#define ANG_HALF 1.5339807878856412e-3f   // pi/2048

// ---------------- Prep: per-(head,pole) quadratic coefficients + Nyquist bin ----------------
// pair(v) at z=iy:  [P1 + i*P0*y] / [(m2 - y^2) + i*(na2*y)]
// na2 = -2a, m2 = a^2+b^2, P0 = 2*vr, P1 = -2*(vr*a + vi*b); all v pre-scaled by dt.
__global__ __launch_bounds__(64) void hippo_prep(
    const float* __restrict__ w_ri,
    const float* __restrict__ P_ri,
    const float* __restrict__ B_ri,
    const float* __restrict__ C_ri,
    const float* __restrict__ log_dt,
    float* __restrict__ coeffs,    // [256][64][12]
    float2* __restrict__ Kf)       // [256][KSTRIDE]
{
    const int h = blockIdx.x;
    const int n = threadIdx.x;
    const float dt = __expf(log_dt[h]);
    const float2 w = ((const float2*)w_ri)[h*NH + n];
    const float2 P = ((const float2*)P_ri)[h*NH + n];
    const float2 B = ((const float2*)B_ri)[h*NH + n];
    const float2 C = ((const float2*)C_ri)[h*NH + n];
    const float a = w.x * dt, b = w.y * dt;
    const float v00r = (B.x*C.x - B.y*C.y) * dt;
    const float v00i = (B.x*C.y + B.y*C.x) * dt;
    const float v01r = (B.x*P.x + B.y*P.y) * dt;   // B*conj(P)
    const float v01i = (B.y*P.x - B.x*P.y) * dt;
    const float v10r = (P.x*C.x - P.y*C.y) * dt;   // P*C
    const float v10i = (P.x*C.y + P.y*C.x) * dt;
    const float v11  = (P.x*P.x + P.y*P.y) * dt;   // |P|^2 (real, imag=0)
    float4* pp = (float4*)(coeffs + (h*NH + n)*12);
    pp[0] = make_float4(-2.f*a, fmaf(a, a, b*b),
                        2.f*v00r, -2.f*fmaf(v00r, a, v00i*b));
    pp[1] = make_float4(2.f*v01r, -2.f*fmaf(v01r, a, v01i*b),
                        2.f*v10r, -2.f*fmaf(v10r, a, v10i*b));
    pp[2] = make_float4(2.f*v11, -2.f*v11*a, 0.f, 0.f);
    // Nyquist bin (z->inf limit): Re(sum v00)
    float s = v00r;
    #pragma unroll
    for (int off = 32; off > 0; off >>= 1) s += __shfl_down(s, off, 64);
    if (n == 0) Kf[h*KSTRIDE + MH] = make_float2(s, 0.f);
}

// ---------------- Cauchy: 4 blocks per head, 256 freqs per block ----------------
__global__ __launch_bounds__(256) void hippo_cauchy(
    const float* __restrict__ coeffs,
    float2* __restrict__ Kf)
{
    const int h = blockIdx.x >> 2;
    const int l = ((blockIdx.x & 3) << 8) | threadIdx.x;   // 0..1023

    float sh, ch;
    __sincosf(ANG_HALF * (float)l, &sh, &ch);
    const float y  = 2.f * sh / ch;          // z = i*y, y = 2*tan(pi*l/2048)
    const float y2 = y * y;
    float r00r=0.f,r00i=0.f,r01r=0.f,r01i=0.f;
    float r10r=0.f,r10i=0.f,r11r=0.f,r11i=0.f;
    const float* pw = coeffs + h*(NH*12);    // wave-uniform base
    #pragma unroll 4
    for (int n = 0; n < NH; ++n) {
        const float4 q0 = *reinterpret_cast<const float4*>(pw + n*12);
        const float4 q1 = *reinterpret_cast<const float4*>(pw + n*12 + 4);
        const float2 q2 = *reinterpret_cast<const float2*>(pw + n*12 + 8);
        const float dr = q0.y - y2;              // m2 - y^2
        const float di = q0.x * y;               // na2 * y
        const float t  = __builtin_amdgcn_rcpf(fmaf(dr, dr, di*di));
        const float U  = dr * t;
        const float V  = di * t;
        const float W  = y * V;
        const float X  = y * U;
        // pair_re = P1*U + P0*W ; pair_im = P0*X - P1*V
        r00r = fmaf(q0.w, U, fmaf(q0.z, W, r00r));
        r00i = fmaf(q0.z, X, fmaf(-q0.w, V, r00i));
        r01r = fmaf(q1.y, U, fmaf(q1.x, W, r01r));
        r01i = fmaf(q1.x, X, fmaf(-q1.y, V, r01i));
        r10r = fmaf(q1.w, U, fmaf(q1.z, W, r10r));
        r10i = fmaf(q1.z, X, fmaf(-q1.w, V, r10i));
        r11r = fmaf(q2.y, U, fmaf(q2.x, W, r11r));
        r11i = fmaf(q2.x, X, fmaf(-q2.y, V, r11i));
    }
    // Woodbury: k0 = r00 - r01*r10/(1+r11)
    const float nr = r01r*r10r - r01i*r10i;
    const float ni = r01r*r10i + r01i*r10r;
    const float dr = 1.f + r11r, di = r11i;
    const float id2 = 1.f / (dr*dr + di*di);
    const float cr = (nr*dr + ni*di)*id2;
    const float ci = (ni*dr - nr*di)*id2;
    const float k0r = r00r - cr, k0i = r00i - ci;
    // * 2/(1+omega) = 1 + i*y/2
    const float hy = 0.5f*y;
    Kf[h*KSTRIDE + l] = make_float2(k0r - k0i*hy, k0i + k0r*hy);
}

// ---------------- iFFT: one head per block ----------------
__global__ __launch_bounds__(1024) void hippo_ifft(
    const float2* __restrict__ Kf,
    float* __restrict__ out)
{
    __shared__ float2 bufA[MH];
    __shared__ float2 bufB[MH];

    const int h   = blockIdx.x;
    const int tid = threadIdx.x;
    const float2* Kh = Kf + h*KSTRIDE;

    // Stage 3a: half-spectrum -> Z[k] for complex IFFT
    // E = (X[k]+conj(X[M-k]))/2, O = e^{+i*pi*k/M}*(X[k]-conj(X[M-k]))/2, Z = E + i*O
    {
        const int k = tid;
        float2 Xk = Kh[k];
        if (k == 0) Xk.y = 0.f;              // bin-0 imag ignored (halfcomplex semantics)
        float2 Xc = Kh[MH - k];
        Xc.y = -Xc.y;
        const float Er = 0.5f*(Xk.x + Xc.x), Ei = 0.5f*(Xk.y + Xc.y);
        const float Tr = 0.5f*(Xk.x - Xc.x), Ti = 0.5f*(Xk.y - Xc.y);
        const float ang = (PI_F/1024.f) * (float)k;
        float sa, ca;
        __sincosf(ang, &sa, &ca);
        const float Or = ca*Tr - sa*Ti;
        const float Oi = ca*Ti + sa*Tr;
        bufA[k] = make_float2(Er - Oi, Ei + Or);
    }
    __syncthreads();

    // Stage 3b: 1024-pt radix-2 Stockham inverse FFT; each thread one point per stage.
    float2* Xb = bufA;
    float2* Yb = bufB;
    int m = 1;
    #pragma unroll
    for (int st = 0; st < 10; ++st) {
        const int o  = tid;
        const int r  = o & (m - 1);
        const int hi = o & m;                    // 0 -> sum output, else twiddled diff
        const int jm = (o >> 1) & ~(m - 1);      // j*m
        const int ti = jm + r;
        const float2 c0 = Xb[ti];
        const float2 c1 = Xb[ti + 512];
        const float ang = (PI_F/512.f) * (float)jm;   // inverse FFT: +angle
        float sw, cw;
        __sincosf(ang, &sw, &cw);
        const float dr = c0.x - c1.x, di = c0.y - c1.y;
        const float tr = cw*dr - sw*di, tii = cw*di + sw*dr;
        const float2 res = hi ? make_float2(tr, tii)
                              : make_float2(c0.x + c1.x, c0.y + c1.y);
        Yb[o] = res;
        __syncthreads();
        float2* t = Xb; Xb = Yb; Yb = t;
        m <<= 1;
    }

    // Stage 3c: interleave + store: x[2n]=Re z[n], x[2n+1]=Im z[n]
    const float sc = 1.0f/1024.0f;
    float2* op2 = (float2*)(out + (size_t)h * LFULL);
    const float2 z = Xb[tid];
    op2[tid] = make_float2(z.x*sc, z.y*sc);
}

extern "C" void kernel_launch(void* const* d_in, const int* in_sizes, int n_in,
                              void* d_out, int out_size, void* d_ws, size_t ws_size,
                              hipStream_t stream) {
    const float* w_ri   = (const float*)d_in[0];
    const float* P_ri   = (const float*)d_in[1];
    const float* B_ri   = (const float*)d_in[2];
    const float* C_ri   = (const float*)d_in[3];
    const float* log_dt = (const float*)d_in[4];
    float* out = (float*)d_out;
    const int Hn = in_sizes[4];   // 256 heads

    float*  coeffs = (float*)d_ws;                          // [H][64][12]
    float2* Kf     = (float2*)(coeffs + (size_t)Hn*NH*12);  // [H][KSTRIDE]

    hippo_prep<<<dim3(Hn), dim3(64), 0, stream>>>(w_ri, P_ri, B_ri, C_ri, log_dt,
                                                  coeffs, Kf);
    hippo_cauchy<<<dim3(Hn*4), dim3(256), 0, stream>>>(coeffs, Kf);
    hippo_ifft<<<dim3(Hn), dim3(1024), 0, stream>>>(Kf, out);
}